// Round 6
// baseline (37.506 us; speedup 1.0000x reference)
//
#include <hip/hip_runtime.h>
#include <math.h>

#define N 4096
#define MARGINF 2.0f
#define EPSF 1e-4f

typedef __fp16   half2v __attribute__((ext_vector_type(2)));  // matches cvt_pkrtz return
typedef _Float16 f16x2  __attribute__((ext_vector_type(2)));  // matches fdot2 operand

__device__ __forceinline__ unsigned h2u(half2v h){ return __builtin_bit_cast(unsigned, h); }
__device__ __forceinline__ half2v  u2h(unsigned u){ return __builtin_bit_cast(half2v, u); }

__device__ __forceinline__ float dot2acc(half2v a, half2v b, float c){
#if __has_builtin(__builtin_amdgcn_fdot2)
    return __builtin_amdgcn_fdot2(__builtin_bit_cast(f16x2, a),
                                  __builtin_bit_cast(f16x2, b), c, false);
#else
    return c + (float)a.x * (float)b.x + (float)a.y * (float)b.y;
#endif
}

constexpr int TILE = 256;                       // row-tile height & col-tile width
constexpr int NT = N / TILE;                    // 16
constexpr int NDIAGTILES = NT * (NT + 1) / 2;   // 136 upper-tri tiles / stream
constexpr int CHUNK = 128;                      // cols per block
constexpr int NSCORE_BLK = 4 * NDIAGTILES * 2;  // 1088 (2 col-halves per tile)
constexpr int NPRED_BLK = NT * (N / CHUNK);     // 16 * 32 = 512
constexpr int NBLK = NSCORE_BLK + NPRED_BLK;    // 1600
constexpr int GRAD_OFF = 2048;                  // float offset of grad partials

// ws layout (floats), all pure-written every call:
//   [0..1087]            score triangle partials (i<j only)
//   [1088..1599]         pred full-matrix partials
//   [GRAD_OFF + r*32+c]  grad partial, pred row r, col-chunk c (c in [0,32))

__global__ __launch_bounds__(256) void pair_kernel(
    const float* __restrict__ scores, const float* __restrict__ pred,
    const float* __restrict__ label, float* __restrict__ ws)
{
    __shared__ unsigned lab16[CHUNK / 2];   // packed fp16 label cols
    __shared__ unsigned col16[CHUNK / 2];   // packed fp16 pred/score cols
    __shared__ float red[4];

    const int bid = blockIdx.x;
    const int tid = threadIdx.x;

    const half2v zero2 = {(__fp16)0.0f, (__fp16)0.0f};
    const half2v one2  = {(__fp16)1.0f, (__fp16)1.0f};
    const half2v two2  = {(__fp16)2.0f, (__fp16)2.0f};
    const half2v big2  = {(__fp16)65504.0f, (__fp16)65504.0f};

    float sum0 = 0.f, sum1 = 0.f;

    if (bid < NSCORE_BLK) {
        // ---- score streams: strict upper-triangle 256x128 half-tiles ----
        const int stream = bid / (NDIAGTILES * 2);
        const int t = bid % (NDIAGTILES * 2);
        int tIdx = t >> 1;
        const int h = t & 1;
        int ti = 0;
        while (tIdx >= NT - ti) { tIdx -= NT - ti; ++ti; }
        const int tj = ti + tIdx;                  // tj >= ti
        const float* __restrict__ p = scores + stream * N;
        const int c0 = tj * TILE + h * CHUNK;

        if (tid < CHUNK / 2) {
            const float2 lf = *(const float2*)&label[c0 + 2 * tid];
            lab16[tid] = h2u(__builtin_amdgcn_cvt_pkrtz(lf.x, lf.y));
        } else if (tid < CHUNK) {
            const int q = tid - CHUNK / 2;
            const float2 pf = *(const float2*)&p[c0 + 2 * q];
            col16[q] = h2u(__builtin_amdgcn_cvt_pkrtz(pf.x, pf.y));
        }
        const int r = ti * TILE + tid;
        const float rkf = p[r];
        const float lkf = label[r];
        const half2v rk2 = __builtin_amdgcn_cvt_pkrtz(rkf, rkf);
        const half2v lk2 = __builtin_amdgcn_cvt_pkrtz(lkf, lkf);
        __syncthreads();

        if (ti != tj) {
            auto body2 = [&](unsigned lm2u, unsigned pm2u, float& acc) {
                const half2v ld2 = u2h(lm2u) - lk2;
                const unsigned sgn = h2u(ld2) & 0x80008000u;
                const half2v pd2 = u2h(pm2u) - rk2;
                const half2v x2 = u2h(h2u(pd2) ^ sgn);
                const half2v m2 = __builtin_elementwise_max(two2 - x2, zero2);
                acc = dot2acc(m2, one2, acc);
            };
            #pragma unroll 4
            for (int q4 = 0; q4 < CHUNK / 8; ++q4) {
                const uint4 l4 = *(const uint4*)&lab16[q4 * 4];
                const uint4 s4 = *(const uint4*)&col16[q4 * 4];
                body2(l4.x, s4.x, sum0); body2(l4.y, s4.y, sum1);
                body2(l4.z, s4.z, sum0); body2(l4.w, s4.w, sum1);
            }
        } else {
            // diagonal tile: only cols with col-in-tile > tid count
            const int cbase = h * CHUNK;
            auto body2m = [&](unsigned lm2u, unsigned pm2u, int cc0, float& acc) {
                const half2v ld2 = u2h(lm2u) - lk2;
                const unsigned sgn = h2u(ld2) & 0x80008000u;
                const half2v pd2 = u2h(pm2u) - rk2;
                const half2v x2 = u2h(h2u(pd2) ^ sgn);
                const half2v m2 = __builtin_elementwise_max(two2 - x2, zero2);
                const unsigned mu = (cc0 + 1 > tid) ? ((cc0 > tid) ? 0x3C003C00u
                                                                   : 0x3C000000u)
                                                    : 0u;
                acc = dot2acc(m2, u2h(mu), acc);
            };
            #pragma unroll 4
            for (int q4 = 0; q4 < CHUNK / 8; ++q4) {
                const uint4 l4 = *(const uint4*)&lab16[q4 * 4];
                const uint4 s4 = *(const uint4*)&col16[q4 * 4];
                const int cc = cbase + q4 * 8;
                body2m(l4.x, s4.x, cc + 0, sum0); body2m(l4.y, s4.y, cc + 2, sum1);
                body2m(l4.z, s4.z, cc + 4, sum0); body2m(l4.w, s4.w, cc + 6, sum1);
            }
        }
    } else {
        // ---- pred stream: full matrix (grad needed), 256x128 chunks ----
        const int rem = bid - NSCORE_BLK;
        const int rowblk = rem >> 5;
        const int ch = rem & 31;
        const int c0 = ch * CHUNK;

        if (tid < CHUNK / 2) {
            const float2 lf = *(const float2*)&label[c0 + 2 * tid];
            lab16[tid] = h2u(__builtin_amdgcn_cvt_pkrtz(lf.x, lf.y));
        } else if (tid < CHUNK) {
            const int q = tid - CHUNK / 2;
            const float2 pf = *(const float2*)&pred[c0 + 2 * q];
            col16[q] = h2u(__builtin_amdgcn_cvt_pkrtz(pf.x, pf.y));
        }
        const int r = rowblk * TILE + tid;
        const float rkf = pred[r];
        const float lkf = label[r];
        const half2v rk2 = __builtin_amdgcn_cvt_pkrtz(rkf, rkf);
        const half2v lk2 = __builtin_amdgcn_cvt_pkrtz(lkf, lkf);
        __syncthreads();

        float grad0 = 0.f, grad1 = 0.f;
        auto body2g = [&](unsigned lm2u, unsigned pm2u, float& acc, float& gacc) {
            const half2v ld2 = u2h(lm2u) - lk2;
            const unsigned sgn = h2u(ld2) & 0x80008000u;
            const half2v pd2 = u2h(pm2u) - rk2;
            const half2v x2 = u2h(h2u(pd2) ^ sgn);
            const half2v m2 = __builtin_elementwise_max(two2 - x2, zero2);
            acc = dot2acc(m2, one2, acc);
            const half2v ind2 = __builtin_elementwise_min(m2 * big2, one2);
            const unsigned su = h2u(ind2) ^ sgn;     // +-indicator
            gacc = dot2acc(u2h(su), one2, gacc);
        };
        #pragma unroll 4
        for (int q4 = 0; q4 < CHUNK / 8; ++q4) {
            const uint4 l4 = *(const uint4*)&lab16[q4 * 4];
            const uint4 s4 = *(const uint4*)&col16[q4 * 4];
            body2g(l4.x, s4.x, sum0, grad0); body2g(l4.y, s4.y, sum1, grad1);
            body2g(l4.z, s4.z, sum0, grad0); body2g(l4.w, s4.w, sum1, grad1);
        }
        float grad = grad0 + grad1;
        // remove spurious diagonal contribution (sign(0)=0 in ref)
        if ((r >> 7) == ch) grad -= 1.0f;
        ws[GRAD_OFF + r * 32 + ch] = grad;
    }

    // block reduce -> one pure store per block
    float sum = sum0 + sum1;
    #pragma unroll
    for (int off = 32; off > 0; off >>= 1)
        sum += __shfl_xor(sum, off, 64);
    const int wid = tid >> 6;
    const int lane = tid & 63;
    if (lane == 0) red[wid] = sum;
    __syncthreads();
    if (tid == 0)
        ws[bid] = red[0] + red[1] + red[2] + red[3];
}

__global__ __launch_bounds__(256) void finalize_kernel(
    const float* __restrict__ pred, const float* __restrict__ label,
    const float* __restrict__ ws, float* __restrict__ out)
{
    __shared__ float lds[16];
    const int tid = threadIdx.x;

    float sse = 0.f, g2sq = 0.f;
    #pragma unroll
    for (int k = 0; k < NT; ++k) {
        const int i = k * 256 + tid;
        const float d = pred[i] - label[i];
        sse += d * d;
        const float4* gp = (const float4*)(ws + GRAD_OFF + i * 32);
        float g = 0.f;
        #pragma unroll
        for (int q = 0; q < 8; ++q) {
            const float4 a = gp[q];
            g += (a.x + a.y) + (a.z + a.w);
        }
        g2sq += g * g;
    }

    float br = ws[tid] + ws[tid + 256] + ws[tid + 512] + ws[tid + 768]
             + ((tid < 64) ? ws[1024 + tid] : 0.f);
    float pr = ws[NSCORE_BLK + tid] + ws[NSCORE_BLK + 256 + tid];

    #pragma unroll
    for (int off = 32; off > 0; off >>= 1) {
        sse  += __shfl_xor(sse,  off, 64);
        g2sq += __shfl_xor(g2sq, off, 64);
        br   += __shfl_xor(br,   off, 64);
        pr   += __shfl_xor(pr,   off, 64);
    }
    const int wid = tid >> 6;
    const int lane = tid & 63;
    if (lane == 0) {
        lds[wid] = sse; lds[4 + wid] = g2sq;
        lds[8 + wid] = br; lds[12 + wid] = pr;
    }
    __syncthreads();
    if (tid == 0) {
        const float sseT  = lds[0] + lds[1] + lds[2] + lds[3];
        const float g2sqT = lds[4] + lds[5] + lds[6] + lds[7];
        const float brT   = lds[8] + lds[9] + lds[10] + lds[11];   // i<j only
        const float prT   = lds[12] + lds[13] + lds[14] + lds[15]; // full matrix
        const float rankp = (prT - (float)N * MARGINF) * 0.5f;
        const float mse = sseT / (float)N;
        const float g1 = (2.0f / (float)N) * sqrtf(sseT);
        const float g2 = sqrtf(g2sqT);
        const float beta = g1 / (g2 + EPSF);
        out[0] = 0.25f * brT + mse + beta * rankp;
    }
}

extern "C" void kernel_launch(void* const* d_in, const int* in_sizes, int n_in,
                              void* d_out, int out_size, void* d_ws, size_t ws_size,
                              hipStream_t stream) {
    const float* scores = (const float*)d_in[0];
    const float* pred   = (const float*)d_in[1];
    const float* label  = (const float*)d_in[2];
    float* ws  = (float*)d_ws;
    float* out = (float*)d_out;

    pair_kernel<<<NBLK, 256, 0, stream>>>(scores, pred, label, ws);
    finalize_kernel<<<1, 256, 0, stream>>>(pred, label, ws, out);
}

// Round 7
// 24.727 us; speedup vs baseline: 1.5168x; 1.5168x over previous
//
#include <hip/hip_runtime.h>
#include <math.h>

#define N 4096
#define MARGINF 2.0f
#define EPSF 1e-4f

typedef _Float16 f16x2 __attribute__((ext_vector_type(2)));  // native arithmetic type

__device__ __forceinline__ unsigned f2u(f16x2 h){ return __builtin_bit_cast(unsigned, h); }
__device__ __forceinline__ f16x2 u2f(unsigned u){ return __builtin_bit_cast(f16x2, u); }
__device__ __forceinline__ unsigned pku(float a, float b){
    return __builtin_bit_cast(unsigned, __builtin_amdgcn_cvt_pkrtz(a, b));
}
__device__ __forceinline__ f16x2 pk2(float a){ return u2f(pku(a, a)); }
__device__ __forceinline__ float fdot2(f16x2 a, f16x2 b, float c){
    return __builtin_amdgcn_fdot2(a, b, c, false);
}
__device__ __forceinline__ f16x2 c_one(){ return u2f(0x3C003C00u); }
__device__ __forceinline__ f16x2 c_two(){ return u2f(0x40004000u); }
__device__ __forceinline__ f16x2 c_zero(){ return u2f(0u); }
__device__ __forceinline__ f16x2 c_big(){ return u2f(0x7BFF7BFFu); } // 65504

constexpr int CC = 128;                        // columns per block (64 packed u32)
constexpr int NCHUNK = N / CC;                 // 32
constexpr int RTS = 1024;                      // score row-tile (4 rows/thread)
constexpr int RTP = 512;                       // pred row-tile (2 rows/thread)
constexpr int SCORE_PER_STREAM = 80;           // sum_{ti=0..3} (32 - 8*ti)
constexpr int NSCORE_BLK = 4 * SCORE_PER_STREAM;      // 320
constexpr int NPRED_BLK = (N / RTP) * NCHUNK;         // 256
constexpr int NBLK = NSCORE_BLK + NPRED_BLK;          // 576
constexpr int PRED_PART = 512;                 // ws float index of pred partials
constexpr int G16_BYTE_OFF = 4096;             // grad16 region (ushort[4096*32])

// ws layout, all pure-written every call:
//   float[0..319]    score triangle partials (i<j only)
//   float[512..767]  pred full-matrix partials
//   bytes [4096 .. 4096+262144)  fp16 grad partials, grad16[row*32 + chunk]

__device__ __forceinline__ void body2(unsigned lm2u, unsigned pm2u,
                                      f16x2 lk2, f16x2 rk2, float& acc){
    const f16x2 ld2 = u2f(lm2u) - lk2;
    const unsigned sgn = f2u(ld2) & 0x80008000u;
    const f16x2 pd2 = u2f(pm2u) - rk2;
    const f16x2 x2 = u2f(f2u(pd2) ^ sgn);
    const f16x2 m2 = __builtin_elementwise_max(c_two() - x2, c_zero());
    acc = fdot2(m2, c_one(), acc);
}

__device__ __forceinline__ void body2m(unsigned lm2u, unsigned pm2u,
                                       f16x2 lk2, f16x2 rk2, int d, float& acc){
    // d = (global col of low half) - (global row); include col iff col > row
    const f16x2 ld2 = u2f(lm2u) - lk2;
    const unsigned sgn = f2u(ld2) & 0x80008000u;
    const f16x2 pd2 = u2f(pm2u) - rk2;
    const f16x2 x2 = u2f(f2u(pd2) ^ sgn);
    const f16x2 m2 = __builtin_elementwise_max(c_two() - x2, c_zero());
    const unsigned mu = (d >= 0) ? ((d > 0) ? 0x3C003C00u : 0x3C000000u) : 0u;
    acc = fdot2(m2, u2f(mu), acc);
}

__device__ __forceinline__ void body2g(unsigned lm2u, unsigned pm2u,
                                       f16x2 lk2, f16x2 rk2, float& acc, float& gacc){
    const f16x2 ld2 = u2f(lm2u) - lk2;
    const unsigned sgn = f2u(ld2) & 0x80008000u;
    const f16x2 pd2 = u2f(pm2u) - rk2;
    const f16x2 x2 = u2f(f2u(pd2) ^ sgn);
    const f16x2 m2 = __builtin_elementwise_max(c_two() - x2, c_zero());
    acc = fdot2(m2, c_one(), acc);
    const f16x2 ind2 = __builtin_elementwise_min(m2 * c_big(), c_one());
    gacc = fdot2(u2f(f2u(ind2) ^ sgn), c_one(), gacc);   // +-indicator
}

__global__ __launch_bounds__(256) void pair_kernel(
    const float* __restrict__ scores, const float* __restrict__ pred,
    const float* __restrict__ label, float* __restrict__ ws)
{
    __shared__ unsigned lab16[CC / 2];
    __shared__ unsigned col16[CC / 2];
    __shared__ float red[4];

    const int bid = blockIdx.x;
    const int tid = threadIdx.x;
    const bool isScore = (bid < NSCORE_BLK);

    // decode block -> (col chunk, row tile, source pointer)
    int ti, c, rb;
    const float* __restrict__ colsrc;
    if (isScore) {
        const int stream = bid / SCORE_PER_STREAM;
        const int b = bid % SCORE_PER_STREAM;
        if      (b < 32) { ti = 0; c = b; }
        else if (b < 56) { ti = 1; c = 8  + (b - 32); }
        else if (b < 72) { ti = 2; c = 16 + (b - 56); }
        else             { ti = 3; c = 24 + (b - 72); }
        rb = ti * RTS;
        colsrc = scores + stream * N;
    } else {
        const int q = bid - NSCORE_BLK;
        ti = q >> 5;             // pred row-tile 0..7
        c  = q & 31;
        rb = ti * RTP;
        colsrc = pred;
    }
    const int c0 = c * CC;

    // stage packed fp16 columns (block-uniform data)
    if (tid < CC / 2) {
        const float2 lf = *(const float2*)&label[c0 + 2 * tid];
        lab16[tid] = pku(lf.x, lf.y);
    } else if (tid < CC) {
        const int q = tid - CC / 2;
        const float2 pf = *(const float2*)&colsrc[c0 + 2 * q];
        col16[q] = pku(pf.x, pf.y);
    }
    __syncthreads();

    float blocksum;

    if (isScore) {
        // 4 rows per thread
        int r[4]; f16x2 rk2[4], lk2[4];
        #pragma unroll
        for (int k = 0; k < 4; ++k) {
            r[k] = rb + tid + 256 * k;
            rk2[k] = pk2(colsrc[r[k]]);
            lk2[k] = pk2(label[r[k]]);
        }
        float acc[8] = {0.f,0.f,0.f,0.f,0.f,0.f,0.f,0.f};

        if (c >= 8 * (ti + 1)) {
            // fully above the diagonal: no mask
            #pragma unroll 4
            for (int q = 0; q < CC / 16; ++q) {
                const uint4 l4a = *(const uint4*)&lab16[q * 8];
                const uint4 s4a = *(const uint4*)&col16[q * 8];
                const uint4 l4b = *(const uint4*)&lab16[q * 8 + 4];
                const uint4 s4b = *(const uint4*)&col16[q * 8 + 4];
                #pragma unroll
                for (int k = 0; k < 4; ++k) {
                    body2(l4a.x, s4a.x, lk2[k], rk2[k], acc[k]);
                    body2(l4a.y, s4a.y, lk2[k], rk2[k], acc[4 + k]);
                    body2(l4a.z, s4a.z, lk2[k], rk2[k], acc[k]);
                    body2(l4a.w, s4a.w, lk2[k], rk2[k], acc[4 + k]);
                    body2(l4b.x, s4b.x, lk2[k], rk2[k], acc[k]);
                    body2(l4b.y, s4b.y, lk2[k], rk2[k], acc[4 + k]);
                    body2(l4b.z, s4b.z, lk2[k], rk2[k], acc[k]);
                    body2(l4b.w, s4b.w, lk2[k], rk2[k], acc[4 + k]);
                }
            }
        } else {
            // diagonal-crossing chunk: per-pair mask col > row
            #pragma unroll 4
            for (int q = 0; q < CC / 8; ++q) {
                const uint4 l4 = *(const uint4*)&lab16[q * 4];
                const uint4 s4 = *(const uint4*)&col16[q * 4];
                const int cb = c0 + q * 8;
                #pragma unroll
                for (int k = 0; k < 4; ++k) {
                    body2m(l4.x, s4.x, lk2[k], rk2[k], cb + 0 - r[k], acc[k]);
                    body2m(l4.y, s4.y, lk2[k], rk2[k], cb + 2 - r[k], acc[4 + k]);
                    body2m(l4.z, s4.z, lk2[k], rk2[k], cb + 4 - r[k], acc[k]);
                    body2m(l4.w, s4.w, lk2[k], rk2[k], cb + 6 - r[k], acc[4 + k]);
                }
            }
        }
        blocksum = (acc[0] + acc[1]) + (acc[2] + acc[3])
                 + (acc[4] + acc[5]) + (acc[6] + acc[7]);
    } else {
        // pred: 2 rows per thread, full matrix, grad accumulated
        int r[2]; f16x2 rk2[2], lk2[2];
        #pragma unroll
        for (int k = 0; k < 2; ++k) {
            r[k] = rb + tid + 256 * k;
            rk2[k] = pk2(pred[r[k]]);
            lk2[k] = pk2(label[r[k]]);
        }
        float acc[4] = {0.f,0.f,0.f,0.f};
        float grd[4] = {0.f,0.f,0.f,0.f};

        #pragma unroll 4
        for (int q = 0; q < CC / 8; ++q) {
            const uint4 l4 = *(const uint4*)&lab16[q * 4];
            const uint4 s4 = *(const uint4*)&col16[q * 4];
            #pragma unroll
            for (int k = 0; k < 2; ++k) {
                body2g(l4.x, s4.x, lk2[k], rk2[k], acc[k],     grd[k]);
                body2g(l4.y, s4.y, lk2[k], rk2[k], acc[2 + k], grd[2 + k]);
                body2g(l4.z, s4.z, lk2[k], rk2[k], acc[k],     grd[k]);
                body2g(l4.w, s4.w, lk2[k], rk2[k], acc[2 + k], grd[2 + k]);
            }
        }
        unsigned short* g16 = (unsigned short*)((char*)ws + G16_BYTE_OFF);
        #pragma unroll
        for (int k = 0; k < 2; ++k) {
            float g = grd[k] + grd[2 + k];
            if ((r[k] >> 7) == c) g -= 1.0f;   // ref: sign(0)=0 on diagonal
            const _Float16 gh = (_Float16)g;   // exact: |g| <= 128, integer
            g16[r[k] * NCHUNK + c] = __builtin_bit_cast(unsigned short, gh);
        }
        blocksum = (acc[0] + acc[1]) + (acc[2] + acc[3]);
    }

    // block reduce -> one pure store per block
    #pragma unroll
    for (int off = 32; off > 0; off >>= 1)
        blocksum += __shfl_xor(blocksum, off, 64);
    const int wid = tid >> 6;
    const int lane = tid & 63;
    if (lane == 0) red[wid] = blocksum;
    __syncthreads();
    if (tid == 0) {
        const float total = red[0] + red[1] + red[2] + red[3];
        if (isScore) ws[bid] = total;
        else         ws[PRED_PART + (bid - NSCORE_BLK)] = total;
    }
}

__global__ __launch_bounds__(256) void finalize_kernel(
    const float* __restrict__ pred, const float* __restrict__ label,
    const float* __restrict__ ws, float* __restrict__ out)
{
    __shared__ float lds[16];
    const int tid = threadIdx.x;
    const unsigned short* g16 = (const unsigned short*)((const char*)ws + G16_BYTE_OFF);

    float sse = 0.f, g2sq = 0.f;
    #pragma unroll
    for (int k = 0; k < 16; ++k) {
        const int i = k * 256 + tid;
        const float d = pred[i] - label[i];
        sse += d * d;
        const uint4* gp = (const uint4*)(g16 + i * NCHUNK);   // 64B per row
        const uint4 a = gp[0], b = gp[1], cq = gp[2], e = gp[3];
        // fp16 partial sums stay integer-exact (<= 1024 per lane)
        const f16x2 s0 = (u2f(a.x) + u2f(a.y)) + (u2f(a.z) + u2f(a.w));
        const f16x2 s1 = (u2f(b.x) + u2f(b.y)) + (u2f(b.z) + u2f(b.w));
        const f16x2 s2 = (u2f(cq.x) + u2f(cq.y)) + (u2f(cq.z) + u2f(cq.w));
        const f16x2 s3 = (u2f(e.x) + u2f(e.y)) + (u2f(e.z) + u2f(e.w));
        const f16x2 t0 = s0 + s1, t1 = s2 + s3;
        const float g = ((float)t0.x + (float)t0.y) + ((float)t1.x + (float)t1.y);
        g2sq += g * g;
    }

    float br = ws[tid] + ((tid < 64) ? ws[256 + tid] : 0.f);   // 320 score partials
    float pr = ws[PRED_PART + tid];                             // 256 pred partials

    #pragma unroll
    for (int off = 32; off > 0; off >>= 1) {
        sse  += __shfl_xor(sse,  off, 64);
        g2sq += __shfl_xor(g2sq, off, 64);
        br   += __shfl_xor(br,   off, 64);
        pr   += __shfl_xor(pr,   off, 64);
    }
    const int wid = tid >> 6;
    const int lane = tid & 63;
    if (lane == 0) {
        lds[wid] = sse; lds[4 + wid] = g2sq;
        lds[8 + wid] = br; lds[12 + wid] = pr;
    }
    __syncthreads();
    if (tid == 0) {
        const float sseT  = lds[0] + lds[1] + lds[2] + lds[3];
        const float g2sqT = lds[4] + lds[5] + lds[6] + lds[7];
        const float brT   = lds[8] + lds[9] + lds[10] + lds[11];   // i<j only
        const float prT   = lds[12] + lds[13] + lds[14] + lds[15]; // full matrix
        const float rankp = (prT - (float)N * MARGINF) * 0.5f;
        const float mse = sseT / (float)N;
        const float g1 = (2.0f / (float)N) * sqrtf(sseT);
        const float g2 = sqrtf(g2sqT);
        const float beta = g1 / (g2 + EPSF);
        out[0] = 0.25f * brT + mse + beta * rankp;
    }
}

extern "C" void kernel_launch(void* const* d_in, const int* in_sizes, int n_in,
                              void* d_out, int out_size, void* d_ws, size_t ws_size,
                              hipStream_t stream) {
    const float* scores = (const float*)d_in[0];
    const float* pred   = (const float*)d_in[1];
    const float* label  = (const float*)d_in[2];
    float* ws  = (float*)d_ws;
    float* out = (float*)d_out;

    pair_kernel<<<NBLK, 256, 0, stream>>>(scores, pred, label, ws);
    finalize_kernel<<<1, 256, 0, stream>>>(pred, label, ws, out);
}